// Round 1
// baseline (2834.078 us; speedup 1.0000x reference)
//
#include <hip/hip_runtime.h>
#include <math.h>

#define N_NODES 50000
#define N_EDGES 800000
#define D 64

__device__ __forceinline__ float rdlane(float x, int k) {
  return __uint_as_float(__builtin_amdgcn_readlane(__float_as_uint(x), k));
}
__device__ __forceinline__ float silu_f(float x) {
  return x / (1.0f + __expf(-x));
}
__device__ __forceinline__ float bfly_sum(float x) {
#pragma unroll
  for (int off = 32; off >= 1; off >>= 1) x += __shfl_xor(x, off, 64);
  return x;
}

// ---------------------------------------------------------------------------
// Kernel 1: per-node hoisted first layer of node MLP: h_ng = s @ ng_w1[:64] + b1
// ---------------------------------------------------------------------------
__global__ void node_pre_kernel(const float* __restrict__ s,
                                const float* __restrict__ ng_w1,
                                const float* __restrict__ ng_b1,
                                float* __restrict__ h_ng) {
  int wave = blockIdx.x * (blockDim.x >> 6) + (threadIdx.x >> 6);
  int d = threadIdx.x & 63;
  if (wave >= N_NODES) return;
  int n = wave;
  float x = s[(size_t)n * D + d];
  float acc = ng_b1[d];
#pragma unroll 16
  for (int k = 0; k < D; ++k) {
    acc += rdlane(x, k) * ng_w1[k * D + d];
  }
  h_ng[(size_t)n * D + d] = acc;
}

// ---------------------------------------------------------------------------
// Kernel 2: edge pipeline. One wave handles 4 edges; lane d = feature d.
// ---------------------------------------------------------------------------
__global__ void edge_kernel(
    const float* __restrict__ v, const int* __restrict__ ei,
    const float* __restrict__ edge_attr, const float* __restrict__ evu,
    const float* __restrict__ ng_w1, const float* __restrict__ ng_w2,
    const float* __restrict__ ng_b2,
    const float* __restrict__ eg_w1, const float* __restrict__ eg_b1,
    const float* __restrict__ eg_w2, const float* __restrict__ eg_b2,
    const float* __restrict__ mg_w1, const float* __restrict__ mg_b1,
    const float* __restrict__ mg_w2, const float* __restrict__ mg_b2,
    const float* __restrict__ pe_w, const float* __restrict__ pe_b,
    const float* __restrict__ h_ng,
    float* __restrict__ s_agg, float* __restrict__ v_agg) {
  int wave = blockIdx.x * (blockDim.x >> 6) + (threadIdx.x >> 6);
  int d = threadIdx.x & 63;
  int g = wave;  // group of 4 edges
  if (g >= N_EDGES / 4) return;

  int row[4], col[4];
  float u0[4], u1[4], u2[4];
  float resij[4], resji[4], cmag[4];
#pragma unroll
  for (int j = 0; j < 4; ++j) {
    int e = g * 4 + j;
    int r = __builtin_amdgcn_readfirstlane(ei[e]);
    int c = __builtin_amdgcn_readfirstlane(ei[N_EDGES + e]);
    row[j] = r; col[j] = c;
    float a0 = evu[e * 3 + 0], a1 = evu[e * 3 + 1], a2 = evu[e * 3 + 2];
    u0[j] = a0; u1[j] = a1; u2[j] = a2;
    float vi0 = v[r * 3 + 0], vi1 = v[r * 3 + 1], vi2 = v[r * 3 + 2];
    float vj0 = v[c * 3 + 0], vj1 = v[c * 3 + 1], vj2 = v[c * 3 + 2];
    resij[j] = 1.0f - (vi0 * a0 + vi1 * a1 + vi2 * a2);
    resji[j] = 1.0f + (vj0 * a0 + vj1 * a1 + vj2 * a2);
    float cx = vi1 * vj2 - vi2 * vj1;
    float cy = vi2 * vj0 - vi0 * vj2;
    float cz = vi0 * vj1 - vi1 * vj0;
    cmag[j] = sqrtf(cx * cx + cy * cy + cz * cz);
  }

  float w1last = ng_w1[D * D + d];  // row 64 of ng_w1 (the `res` column weight)

  // a_i, a_j : silu(first layer) using hoisted h_ng
  float ai[4], aj[4];
#pragma unroll
  for (int j = 0; j < 4; ++j) {
    ai[j] = silu_f(h_ng[(size_t)row[j] * D + d] + resij[j] * w1last);
    aj[j] = silu_f(h_ng[(size_t)col[j] * D + d] + resji[j] * w1last);
  }

  // nf_i, nf_j = a @ ng_w2 + ng_b2  (shared weight load, reused x8)
  float nfi[4], nfj[4];
  {
    float b2 = ng_b2[d];
#pragma unroll
    for (int j = 0; j < 4; ++j) { nfi[j] = b2; nfj[j] = b2; }
#pragma unroll 8
    for (int k = 0; k < D; ++k) {
      float w = ng_w2[k * D + d];
#pragma unroll
      for (int j = 0; j < 4; ++j) {
        nfi[j] += rdlane(ai[j], k) * w;
        nfj[j] += rdlane(aj[j], k) * w;
      }
    }
  }

  // edge_feat = MLP2([edge_attr, cross_mag]; eg)
  float ef[4];
  {
    float xe[4];
#pragma unroll
    for (int j = 0; j < 4; ++j) xe[j] = edge_attr[(size_t)(g * 4 + j) * D + d];
    float ae[4];
    float egb1 = eg_b1[d], wlast = eg_w1[D * D + d];
#pragma unroll
    for (int j = 0; j < 4; ++j) ae[j] = egb1 + cmag[j] * wlast;
#pragma unroll 8
    for (int k = 0; k < D; ++k) {
      float w = eg_w1[k * D + d];
#pragma unroll
      for (int j = 0; j < 4; ++j) ae[j] += rdlane(xe[j], k) * w;
    }
#pragma unroll
    for (int j = 0; j < 4; ++j) ae[j] = silu_f(ae[j]);
    float egb2 = eg_b2[d];
#pragma unroll
    for (int j = 0; j < 4; ++j) ef[j] = egb2;
#pragma unroll 8
    for (int k = 0; k < D; ++k) {
      float w = eg_w2[k * D + d];
#pragma unroll
      for (int j = 0; j < 4; ++j) ef[j] += rdlane(ae[j], k) * w;
    }
  }

  // msg hidden layer (192 -> 128): lane d owns hidden units 2d and 2d+1
  float2 h1[4];
  {
    float2 mb1 = *(const float2*)&mg_b1[2 * d];
#pragma unroll
    for (int j = 0; j < 4; ++j) h1[j] = mb1;
#pragma unroll 8
    for (int k = 0; k < D; ++k) {
      float2 w = *(const float2*)&mg_w1[(size_t)k * 128 + 2 * d];
#pragma unroll
      for (int j = 0; j < 4; ++j) {
        float sv = rdlane(nfi[j], k);
        h1[j].x += sv * w.x; h1[j].y += sv * w.y;
      }
    }
#pragma unroll 8
    for (int k = 0; k < D; ++k) {
      float2 w = *(const float2*)&mg_w1[(size_t)(D + k) * 128 + 2 * d];
#pragma unroll
      for (int j = 0; j < 4; ++j) {
        float sv = rdlane(nfj[j], k);
        h1[j].x += sv * w.x; h1[j].y += sv * w.y;
      }
    }
#pragma unroll 8
    for (int k = 0; k < D; ++k) {
      float2 w = *(const float2*)&mg_w1[(size_t)(2 * D + k) * 128 + 2 * d];
#pragma unroll
      for (int j = 0; j < 4; ++j) {
        float sv = rdlane(ef[j], k);
        h1[j].x += sv * w.x; h1[j].y += sv * w.y;
      }
    }
#pragma unroll
    for (int j = 0; j < 4; ++j) {
      h1[j].x = silu_f(h1[j].x);
      h1[j].y = silu_f(h1[j].y);
    }
  }

  // msg (128 -> 64)
  float msg[4];
  {
    float mb2 = mg_b2[d];
#pragma unroll
    for (int j = 0; j < 4; ++j) msg[j] = mb2;
#pragma unroll 8
    for (int m = 0; m < D; ++m) {
      float wa = mg_w2[(size_t)(2 * m) * D + d];
      float wb = mg_w2[(size_t)(2 * m + 1) * D + d];
#pragma unroll
      for (int j = 0; j < 4; ++j) {
        msg[j] += rdlane(h1[j].x, m) * wa + rdlane(h1[j].y, m) * wb;
      }
    }
  }

  // coeff + scatter
  float pw = pe_w[d];
  float pb = pe_b[0];
#pragma unroll
  for (int j = 0; j < 4; ++j) {
    float coeff = bfly_sum(msg[j] * pw) + pb;
    atomicAdd(&s_agg[(size_t)row[j] * D + d], msg[j]);
    if (d < 3) {
      float uc = (d == 0) ? u0[j] : ((d == 1) ? u1[j] : u2[j]);
      atomicAdd(&v_agg[(size_t)row[j] * 3 + d], uc * coeff);
    }
  }
}

// ---------------------------------------------------------------------------
// Kernel 3: node update + layernorm + v normalize
// ---------------------------------------------------------------------------
__global__ void node_out_kernel(
    const float* __restrict__ s, const float* __restrict__ v,
    const float* __restrict__ up_w, const float* __restrict__ up_b,
    const float* __restrict__ ln_g, const float* __restrict__ ln_b,
    const float* __restrict__ s_agg, const float* __restrict__ v_agg,
    float* __restrict__ out) {
  int wave = blockIdx.x * (blockDim.x >> 6) + (threadIdx.x >> 6);
  int d = threadIdx.x & 63;
  if (wave >= N_NODES) return;
  int n = wave;

  float g = silu_f(s_agg[(size_t)n * D + d]);
  float acc = up_b[d];
#pragma unroll 16
  for (int k = 0; k < D; ++k) acc += rdlane(g, k) * up_w[k * D + d];
  float s_new = s[(size_t)n * D + d] + acc;

  float mu = bfly_sum(s_new) * (1.0f / 64.0f);
  float diff = s_new - mu;
  float var = bfly_sum(diff * diff) * (1.0f / 64.0f);
  float inv = 1.0f / sqrtf(var + 1e-5f);
  out[(size_t)n * D + d] = diff * inv * ln_g[d] + ln_b[d];

  if (d < 3) {
    float v0 = v[n * 3 + 0] + v_agg[(size_t)n * 3 + 0];
    float v1 = v[n * 3 + 1] + v_agg[(size_t)n * 3 + 1];
    float v2 = v[n * 3 + 2] + v_agg[(size_t)n * 3 + 2];
    float nrm = sqrtf(v0 * v0 + v1 * v1 + v2 * v2);
    float denom = fmaxf(nrm, 1e-6f);
    float val = (d == 0) ? v0 : ((d == 1) ? v1 : v2);
    out[(size_t)N_NODES * D + (size_t)n * 3 + d] = val / denom;
  }
}

// ---------------------------------------------------------------------------
extern "C" void kernel_launch(void* const* d_in, const int* in_sizes, int n_in,
                              void* d_out, int out_size, void* d_ws, size_t ws_size,
                              hipStream_t stream) {
  const float* s         = (const float*)d_in[0];
  const float* v         = (const float*)d_in[1];
  const int*   ei        = (const int*)d_in[2];
  const float* edge_attr = (const float*)d_in[3];
  const float* evu       = (const float*)d_in[4];
  const float* ng_w1     = (const float*)d_in[5];
  const float* ng_b1     = (const float*)d_in[6];
  const float* ng_w2     = (const float*)d_in[7];
  const float* ng_b2     = (const float*)d_in[8];
  const float* eg_w1     = (const float*)d_in[9];
  const float* eg_b1     = (const float*)d_in[10];
  const float* eg_w2     = (const float*)d_in[11];
  const float* eg_b2     = (const float*)d_in[12];
  const float* mg_w1     = (const float*)d_in[13];
  const float* mg_b1     = (const float*)d_in[14];
  const float* mg_w2     = (const float*)d_in[15];
  const float* mg_b2     = (const float*)d_in[16];
  const float* pe_w      = (const float*)d_in[17];
  const float* pe_b      = (const float*)d_in[18];
  const float* up_w      = (const float*)d_in[19];
  const float* up_b      = (const float*)d_in[20];
  const float* ln_g      = (const float*)d_in[21];
  const float* ln_b      = (const float*)d_in[22];
  (void)in_sizes; (void)n_in; (void)out_size; (void)ws_size;

  float* out   = (float*)d_out;
  float* s_agg = (float*)d_ws;                       // N*64 floats
  float* v_agg = s_agg + (size_t)N_NODES * D;        // N*3 floats
  float* h_ng  = out;  // reuse d_out[0 .. N*64) as scratch; node_out overwrites later

  // zero the aggregation buffers (ws is poisoned 0xAA before every launch)
  hipMemsetAsync(d_ws, 0, (size_t)(N_NODES * D + N_NODES * 3) * sizeof(float), stream);

  // 50000 waves, 4 waves per 256-thread block
  node_pre_kernel<<<(N_NODES + 3) / 4, 256, 0, stream>>>(s, ng_w1, ng_b1, h_ng);

  // 200000 edge groups of 4, 4 waves/block -> 50000 blocks
  edge_kernel<<<N_EDGES / 4 / 4, 256, 0, stream>>>(
      v, ei, edge_attr, evu,
      ng_w1, ng_w2, ng_b2,
      eg_w1, eg_b1, eg_w2, eg_b2,
      mg_w1, mg_b1, mg_w2, mg_b2,
      pe_w, pe_b, h_ng, s_agg, v_agg);

  node_out_kernel<<<(N_NODES + 3) / 4, 256, 0, stream>>>(
      s, v, up_w, up_b, ln_g, ln_b, s_agg, v_agg, out);
}

// Round 2
// 839.751 us; speedup vs baseline: 3.3749x; 3.3749x over previous
//
#include <hip/hip_runtime.h>
#include <math.h>

#define NN 50000
#define NE 800000
#define D 64
#define TILE 64

typedef __attribute__((ext_vector_type(8))) short short8;
typedef __attribute__((ext_vector_type(4))) float f32x4;

__device__ __forceinline__ float rdlane(float x, int k) {
  return __uint_as_float(__builtin_amdgcn_readlane(__float_as_uint(x), k));
}
__device__ __forceinline__ float silu_f(float x) { return x / (1.0f + __expf(-x)); }
__device__ __forceinline__ float bfly_sum(float x) {
#pragma unroll
  for (int off = 32; off >= 1; off >>= 1) x += __shfl_xor(x, off, 64);
  return x;
}
__device__ __forceinline__ unsigned short f2bf(float f) {
  unsigned int u = __float_as_uint(f);
  u += 0x7fffu + ((u >> 16) & 1u);
  return (unsigned short)(u >> 16);
}
__device__ __forceinline__ unsigned int pack2(float a, float b) {
  return (unsigned int)f2bf(a) | ((unsigned int)f2bf(b) << 16);
}

// ---------------------------------------------------------------------------
// prep: permute fp32 weight W[K][N] into bf16 MFMA B-fragments.
// frag (nt, ks): 64 lanes x 8 elems; elem(L,j) = W[ks*32 + (L>>4)*8 + j][nt*16 + (L&15)]
// stored at out[frag*512 + L*8 + j], frag = nt*(K/32) + ks
// ---------------------------------------------------------------------------
__global__ void prep_frags(const float* __restrict__ W, int K, int N,
                           unsigned short* __restrict__ out) {
  int tid = blockIdx.x * 256 + threadIdx.x;
  int kd = K >> 5;
  int nfrag = kd * (N >> 4);
  if (tid >= nfrag * 64) return;
  int frag = tid >> 6, L = tid & 63;
  int nt = frag / kd, ks = frag % kd;
  int kb = ks * 32 + (L >> 4) * 8;
  int nc = nt * 16 + (L & 15);
  unsigned int p[4];
#pragma unroll
  for (int jj = 0; jj < 4; ++jj) {
    float a = W[(size_t)(kb + 2 * jj) * N + nc];
    float b = W[(size_t)(kb + 2 * jj + 1) * N + nc];
    p[jj] = pack2(a, b);
  }
  *(uint4*)(out + (size_t)frag * 512 + L * 8) = make_uint4(p[0], p[1], p[2], p[3]);
}

// ---------------------------------------------------------------------------
// Kernel 1: per-node hoisted first layer of node MLP: h_ng = s @ ng_w1[:64] + b1
// ---------------------------------------------------------------------------
__global__ void node_pre_kernel(const float* __restrict__ s,
                                const float* __restrict__ ng_w1,
                                const float* __restrict__ ng_b1,
                                float* __restrict__ h_ng) {
  int wave = blockIdx.x * (blockDim.x >> 6) + (threadIdx.x >> 6);
  int d = threadIdx.x & 63;
  if (wave >= NN) return;
  float x = s[(size_t)wave * D + d];
  float acc = ng_b1[d];
#pragma unroll 16
  for (int k = 0; k < D; ++k) acc += rdlane(x, k) * ng_w1[k * D + d];
  h_ng[(size_t)wave * D + d] = acc;
}

// ---------------------------------------------------------------------------
// Kernel 2: MFMA edge pipeline. Block = 4 waves, tile = 64 edges.
// Wave w owns output cols [w*16, w*16+16) of each layer.
// ---------------------------------------------------------------------------
#define OFF_A0 0
#define OFF_A1 9216
#define OFF_C1 18432
#define OFF_XE 44032
#define OFF_AE 53248
#define OFF_H  44032
#define OFF_ROW 62464
#define OFF_COL 62720
#define OFF_RIJ 62976
#define OFF_RJI 63232
#define OFF_CMG 63488
#define OFF_U   63744
#define OFF_CP  64512
#define SA 144
#define SC 400
#define SH 272

__global__ __launch_bounds__(256, 2) void edge_mfma(
    const float* __restrict__ v, const int* __restrict__ ei,
    const float* __restrict__ edge_attr, const float* __restrict__ evu,
    const float* __restrict__ ng_w1, const float* __restrict__ ng_b2,
    const float* __restrict__ eg_w1, const float* __restrict__ eg_b1,
    const float* __restrict__ eg_b2,
    const float* __restrict__ mg_b1, const float* __restrict__ mg_b2,
    const float* __restrict__ pe_w, const float* __restrict__ pe_b,
    const float* __restrict__ h_ng,
    const unsigned short* __restrict__ WF,
    float* __restrict__ s_agg, float* __restrict__ v_agg) {
  __shared__ __align__(16) char sm[65536];
  int tid = threadIdx.x;
  int w = tid >> 6, lane = tid & 63, l15 = lane & 15, quad = lane >> 4;
  int edge0 = blockIdx.x * TILE;

  // ---- weight fragments, held in registers for the whole kernel ----
  short8 F_ng[2], F_e1[2], F_e2[2], F_m1[2][6], F_m2[4];
#pragma unroll
  for (int k = 0; k < 2; ++k) {
    F_ng[k] = *(const short8*)(WF + (size_t)(0 + w * 2 + k) * 512 + lane * 8);
    F_e1[k] = *(const short8*)(WF + (size_t)(8 + w * 2 + k) * 512 + lane * 8);
    F_e2[k] = *(const short8*)(WF + (size_t)(16 + w * 2 + k) * 512 + lane * 8);
  }
#pragma unroll
  for (int n2 = 0; n2 < 2; ++n2)
#pragma unroll
    for (int k = 0; k < 6; ++k)
      F_m1[n2][k] = *(const short8*)(WF + (size_t)(24 + (2 * w + n2) * 6 + k) * 512 + lane * 8);
#pragma unroll
  for (int k = 0; k < 4; ++k)
    F_m2[k] = *(const short8*)(WF + (size_t)(72 + w * 4 + k) * 512 + lane * 8);

  int col = w * 16 + l15;
  float b_ng2 = ng_b2[col];
  float b_e1 = eg_b1[col], b_e2 = eg_b2[col];
  float eglast = eg_w1[64 * 64 + col];
  float b_m1a = mg_b1[w * 32 + l15], b_m1b = mg_b1[w * 32 + 16 + l15];
  float b_m2 = mg_b2[col];
  float pw = pe_w[col];
  float peb = pe_b[0];

  // ---- phase A: per-edge scalars ----
  if (tid < 64) {
    int e = tid, ed = edge0 + e;
    int r = ei[ed], c = ei[NE + ed];
    float u0 = evu[ed * 3 + 0], u1 = evu[ed * 3 + 1], u2 = evu[ed * 3 + 2];
    float vi0 = v[r * 3 + 0], vi1 = v[r * 3 + 1], vi2 = v[r * 3 + 2];
    float vj0 = v[c * 3 + 0], vj1 = v[c * 3 + 1], vj2 = v[c * 3 + 2];
    ((int*)(sm + OFF_ROW))[e] = r;
    ((int*)(sm + OFF_COL))[e] = c;
    ((float*)(sm + OFF_RIJ))[e] = 1.0f - (vi0 * u0 + vi1 * u1 + vi2 * u2);
    ((float*)(sm + OFF_RJI))[e] = 1.0f + (vj0 * u0 + vj1 * u1 + vj2 * u2);
    float cx = vi1 * vj2 - vi2 * vj1;
    float cy = vi2 * vj0 - vi0 * vj2;
    float cz = vi0 * vj1 - vi1 * vj0;
    ((float*)(sm + OFF_CMG))[e] = sqrtf(cx * cx + cy * cy + cz * cz);
    ((float*)(sm + OFF_U))[e * 3 + 0] = u0;
    ((float*)(sm + OFF_U))[e * 3 + 1] = u1;
    ((float*)(sm + OFF_U))[e * 3 + 2] = u2;
  }
  __syncthreads();

  // ---- phase B: stage a_i, a_j, Xe as bf16 into LDS ----
  {
    int e = tid >> 2, fq = (tid & 3) * 16;
    int rr = ((const int*)(sm + OFF_ROW))[e];
    int cc = ((const int*)(sm + OFF_COL))[e];
    float rij = ((const float*)(sm + OFF_RIJ))[e];
    float rji = ((const float*)(sm + OFF_RJI))[e];
    f32x4 wl[4];
#pragma unroll
    for (int q = 0; q < 4; ++q) wl[q] = *(const f32x4*)(ng_w1 + 64 * 64 + fq + q * 4);

    float va[16];
#pragma unroll
    for (int q = 0; q < 4; ++q) {
      f32x4 h = *(const f32x4*)(h_ng + (size_t)rr * D + fq + q * 4);
#pragma unroll
      for (int c2 = 0; c2 < 4; ++c2) va[q * 4 + c2] = silu_f(h[c2] + rij * wl[q][c2]);
    }
    *(uint4*)(sm + OFF_A0 + e * SA + fq * 2) =
        make_uint4(pack2(va[0], va[1]), pack2(va[2], va[3]), pack2(va[4], va[5]), pack2(va[6], va[7]));
    *(uint4*)(sm + OFF_A0 + e * SA + fq * 2 + 16) =
        make_uint4(pack2(va[8], va[9]), pack2(va[10], va[11]), pack2(va[12], va[13]), pack2(va[14], va[15]));

#pragma unroll
    for (int q = 0; q < 4; ++q) {
      f32x4 h = *(const f32x4*)(h_ng + (size_t)cc * D + fq + q * 4);
#pragma unroll
      for (int c2 = 0; c2 < 4; ++c2) va[q * 4 + c2] = silu_f(h[c2] + rji * wl[q][c2]);
    }
    *(uint4*)(sm + OFF_A1 + e * SA + fq * 2) =
        make_uint4(pack2(va[0], va[1]), pack2(va[2], va[3]), pack2(va[4], va[5]), pack2(va[6], va[7]));
    *(uint4*)(sm + OFF_A1 + e * SA + fq * 2 + 16) =
        make_uint4(pack2(va[8], va[9]), pack2(va[10], va[11]), pack2(va[12], va[13]), pack2(va[14], va[15]));

#pragma unroll
    for (int q = 0; q < 4; ++q) {
      f32x4 x = *(const f32x4*)(edge_attr + (size_t)(edge0 + e) * D + fq + q * 4);
#pragma unroll
      for (int c2 = 0; c2 < 4; ++c2) va[q * 4 + c2] = x[c2];
    }
    *(uint4*)(sm + OFF_XE + e * SA + fq * 2) =
        make_uint4(pack2(va[0], va[1]), pack2(va[2], va[3]), pack2(va[4], va[5]), pack2(va[6], va[7]));
    *(uint4*)(sm + OFF_XE + e * SA + fq * 2 + 16) =
        make_uint4(pack2(va[8], va[9]), pack2(va[10], va[11]), pack2(va[12], va[13]), pack2(va[14], va[15]));
  }
  __syncthreads();

  // ---- nf_i, nf_j -> C1 cols [0,64) and [64,128) ; ae -> Ae ----
#pragma unroll
  for (int mt = 0; mt < 4; ++mt) {
    f32x4 acc = {0.f, 0.f, 0.f, 0.f};
    short8 a0 = *(const short8*)(sm + OFF_A0 + (mt * 16 + l15) * SA + quad * 16);
    short8 a1 = *(const short8*)(sm + OFF_A0 + (mt * 16 + l15) * SA + 64 + quad * 16);
    acc = __builtin_amdgcn_mfma_f32_16x16x32_bf16(a0, F_ng[0], acc, 0, 0, 0);
    acc = __builtin_amdgcn_mfma_f32_16x16x32_bf16(a1, F_ng[1], acc, 0, 0, 0);
    int e0 = mt * 16 + quad * 4;
#pragma unroll
    for (int r = 0; r < 4; ++r)
      *(unsigned short*)(sm + OFF_C1 + (e0 + r) * SC + col * 2) = f2bf(acc[r] + b_ng2);
  }
#pragma unroll
  for (int mt = 0; mt < 4; ++mt) {
    f32x4 acc = {0.f, 0.f, 0.f, 0.f};
    short8 a0 = *(const short8*)(sm + OFF_A1 + (mt * 16 + l15) * SA + quad * 16);
    short8 a1 = *(const short8*)(sm + OFF_A1 + (mt * 16 + l15) * SA + 64 + quad * 16);
    acc = __builtin_amdgcn_mfma_f32_16x16x32_bf16(a0, F_ng[0], acc, 0, 0, 0);
    acc = __builtin_amdgcn_mfma_f32_16x16x32_bf16(a1, F_ng[1], acc, 0, 0, 0);
    int e0 = mt * 16 + quad * 4;
#pragma unroll
    for (int r = 0; r < 4; ++r)
      *(unsigned short*)(sm + OFF_C1 + (e0 + r) * SC + (64 + col) * 2) = f2bf(acc[r] + b_ng2);
  }
#pragma unroll
  for (int mt = 0; mt < 4; ++mt) {
    f32x4 acc = {0.f, 0.f, 0.f, 0.f};
    short8 a0 = *(const short8*)(sm + OFF_XE + (mt * 16 + l15) * SA + quad * 16);
    short8 a1 = *(const short8*)(sm + OFF_XE + (mt * 16 + l15) * SA + 64 + quad * 16);
    acc = __builtin_amdgcn_mfma_f32_16x16x32_bf16(a0, F_e1[0], acc, 0, 0, 0);
    acc = __builtin_amdgcn_mfma_f32_16x16x32_bf16(a1, F_e1[1], acc, 0, 0, 0);
    int e0 = mt * 16 + quad * 4;
#pragma unroll
    for (int r = 0; r < 4; ++r) {
      float cm = ((const float*)(sm + OFF_CMG))[e0 + r];
      *(unsigned short*)(sm + OFF_AE + (e0 + r) * SA + col * 2) =
          f2bf(silu_f(acc[r] + b_e1 + cm * eglast));
    }
  }
  __syncthreads();

  // ---- ef = Ae @ eg_w2 -> C1 cols [128,192) ----
#pragma unroll
  for (int mt = 0; mt < 4; ++mt) {
    f32x4 acc = {0.f, 0.f, 0.f, 0.f};
    short8 a0 = *(const short8*)(sm + OFF_AE + (mt * 16 + l15) * SA + quad * 16);
    short8 a1 = *(const short8*)(sm + OFF_AE + (mt * 16 + l15) * SA + 64 + quad * 16);
    acc = __builtin_amdgcn_mfma_f32_16x16x32_bf16(a0, F_e2[0], acc, 0, 0, 0);
    acc = __builtin_amdgcn_mfma_f32_16x16x32_bf16(a1, F_e2[1], acc, 0, 0, 0);
    int e0 = mt * 16 + quad * 4;
#pragma unroll
    for (int r = 0; r < 4; ++r)
      *(unsigned short*)(sm + OFF_C1 + (e0 + r) * SC + (128 + col) * 2) = f2bf(acc[r] + b_e2);
  }
  __syncthreads();

  // ---- h1 = silu(C1[64x192] @ mg_w1) -> H (wave owns 32 cols) ----
#pragma unroll
  for (int n2 = 0; n2 < 2; ++n2) {
    int colh = w * 32 + n2 * 16 + l15;
    float bb = n2 ? b_m1b : b_m1a;
#pragma unroll
    for (int mt = 0; mt < 4; ++mt) {
      f32x4 acc = {0.f, 0.f, 0.f, 0.f};
#pragma unroll
      for (int ks = 0; ks < 6; ++ks) {
        short8 a = *(const short8*)(sm + OFF_C1 + (mt * 16 + l15) * SC + ks * 64 + quad * 16);
        acc = __builtin_amdgcn_mfma_f32_16x16x32_bf16(a, F_m1[n2][ks], acc, 0, 0, 0);
      }
      int e0 = mt * 16 + quad * 4;
#pragma unroll
      for (int r = 0; r < 4; ++r)
        *(unsigned short*)(sm + OFF_H + (e0 + r) * SH + colh * 2) = f2bf(silu_f(acc[r] + bb));
    }
  }
  __syncthreads();

  // ---- msg = H @ mg_w2 + b2 ; coeff partials ; scatter s_agg ----
#pragma unroll
  for (int mt = 0; mt < 4; ++mt) {
    f32x4 acc = {0.f, 0.f, 0.f, 0.f};
#pragma unroll
    for (int ks = 0; ks < 4; ++ks) {
      short8 a = *(const short8*)(sm + OFF_H + (mt * 16 + l15) * SH + ks * 64 + quad * 16);
      acc = __builtin_amdgcn_mfma_f32_16x16x32_bf16(a, F_m2[ks], acc, 0, 0, 0);
    }
    int e0 = mt * 16 + quad * 4;
#pragma unroll
    for (int r = 0; r < 4; ++r) {
      float m = acc[r] + b_m2;
      float p = m * pw;
      p += __shfl_xor(p, 1, 64);
      p += __shfl_xor(p, 2, 64);
      p += __shfl_xor(p, 4, 64);
      p += __shfl_xor(p, 8, 64);
      if (l15 == 0) ((float*)(sm + OFF_CP))[(e0 + r) * 4 + w] = p;
      int rn = ((const int*)(sm + OFF_ROW))[e0 + r];
      atomicAdd(&s_agg[(size_t)rn * D + col], m);
    }
  }
  __syncthreads();

  // ---- phase D: v_agg scatter ----
  if (tid < 64) {
    const float* cp = (const float*)(sm + OFF_CP);
    float c = cp[tid * 4] + cp[tid * 4 + 1] + cp[tid * 4 + 2] + cp[tid * 4 + 3] + peb;
    int rn = ((const int*)(sm + OFF_ROW))[tid];
    const float* uu = (const float*)(sm + OFF_U);
    atomicAdd(&v_agg[rn * 3 + 0], uu[tid * 3 + 0] * c);
    atomicAdd(&v_agg[rn * 3 + 1], uu[tid * 3 + 1] * c);
    atomicAdd(&v_agg[rn * 3 + 2], uu[tid * 3 + 2] * c);
  }
}

// ---------------------------------------------------------------------------
// Kernel 3: node update + layernorm + v normalize
// ---------------------------------------------------------------------------
__global__ void node_out_kernel(
    const float* __restrict__ s, const float* __restrict__ v,
    const float* __restrict__ up_w, const float* __restrict__ up_b,
    const float* __restrict__ ln_g, const float* __restrict__ ln_b,
    const float* __restrict__ s_agg, const float* __restrict__ v_agg,
    float* __restrict__ out) {
  int wave = blockIdx.x * (blockDim.x >> 6) + (threadIdx.x >> 6);
  int d = threadIdx.x & 63;
  if (wave >= NN) return;
  int n = wave;

  float g = silu_f(s_agg[(size_t)n * D + d]);
  float acc = up_b[d];
#pragma unroll 16
  for (int k = 0; k < D; ++k) acc += rdlane(g, k) * up_w[k * D + d];
  float s_new = s[(size_t)n * D + d] + acc;

  float mu = bfly_sum(s_new) * (1.0f / 64.0f);
  float diff = s_new - mu;
  float var = bfly_sum(diff * diff) * (1.0f / 64.0f);
  float inv = 1.0f / sqrtf(var + 1e-5f);
  out[(size_t)n * D + d] = diff * inv * ln_g[d] + ln_b[d];

  if (d < 3) {
    float v0 = v[n * 3 + 0] + v_agg[(size_t)n * 3 + 0];
    float v1 = v[n * 3 + 1] + v_agg[(size_t)n * 3 + 1];
    float v2 = v[n * 3 + 2] + v_agg[(size_t)n * 3 + 2];
    float nrm = sqrtf(v0 * v0 + v1 * v1 + v2 * v2);
    float denom = fmaxf(nrm, 1e-6f);
    float val = (d == 0) ? v0 : ((d == 1) ? v1 : v2);
    out[(size_t)NN * D + (size_t)n * 3 + d] = val / denom;
  }
}

// ---------------------------------------------------------------------------
extern "C" void kernel_launch(void* const* d_in, const int* in_sizes, int n_in,
                              void* d_out, int out_size, void* d_ws, size_t ws_size,
                              hipStream_t stream) {
  const float* s         = (const float*)d_in[0];
  const float* v         = (const float*)d_in[1];
  const int*   ei        = (const int*)d_in[2];
  const float* edge_attr = (const float*)d_in[3];
  const float* evu       = (const float*)d_in[4];
  const float* ng_w1     = (const float*)d_in[5];
  const float* ng_b1     = (const float*)d_in[6];
  const float* ng_w2     = (const float*)d_in[7];
  const float* ng_b2     = (const float*)d_in[8];
  const float* eg_w1     = (const float*)d_in[9];
  const float* eg_b1     = (const float*)d_in[10];
  const float* eg_w2     = (const float*)d_in[11];
  const float* eg_b2     = (const float*)d_in[12];
  const float* mg_w1     = (const float*)d_in[13];
  const float* mg_b1     = (const float*)d_in[14];
  const float* mg_w2     = (const float*)d_in[15];
  const float* mg_b2     = (const float*)d_in[16];
  const float* pe_w      = (const float*)d_in[17];
  const float* pe_b      = (const float*)d_in[18];
  const float* up_w      = (const float*)d_in[19];
  const float* up_b      = (const float*)d_in[20];
  const float* ln_g      = (const float*)d_in[21];
  const float* ln_b      = (const float*)d_in[22];
  (void)in_sizes; (void)n_in; (void)out_size; (void)ws_size;

  float* out   = (float*)d_out;
  float* s_agg = (float*)d_ws;                            // NN*64 floats
  float* v_agg = s_agg + (size_t)NN * D;                  // NN*3 floats
  unsigned short* WF = (unsigned short*)(v_agg + (size_t)NN * 3);  // 88 frags * 512 bf16
  float* h_ng  = out;  // reuse d_out as scratch for hoisted node-MLP layer

  hipMemsetAsync(d_ws, 0, (size_t)(NN * D + NN * 3) * sizeof(float), stream);

  // weight fragment prep (tiny)
  prep_frags<<<2, 256, 0, stream>>>(ng_w2, 64, 64, WF + 0 * 512);
  prep_frags<<<2, 256, 0, stream>>>(eg_w1, 64, 64, WF + 8 * 512);
  prep_frags<<<2, 256, 0, stream>>>(eg_w2, 64, 64, WF + 16 * 512);
  prep_frags<<<12, 256, 0, stream>>>(mg_w1, 192, 128, WF + 24 * 512);
  prep_frags<<<4, 256, 0, stream>>>(mg_w2, 128, 64, WF + 72 * 512);

  node_pre_kernel<<<(NN + 3) / 4, 256, 0, stream>>>(s, ng_w1, ng_b1, h_ng);

  edge_mfma<<<NE / TILE, 256, 0, stream>>>(
      v, ei, edge_attr, evu,
      ng_w1, ng_b2, eg_w1, eg_b1, eg_b2,
      mg_b1, mg_b2, pe_w, pe_b, h_ng, WF, s_agg, v_agg);

  node_out_kernel<<<(NN + 3) / 4, 256, 0, stream>>>(
      s, v, up_w, up_b, ln_g, ln_b, s_agg, v_agg, out);
}

// Round 3
// 694.528 us; speedup vs baseline: 4.0806x; 1.2091x over previous
//
#include <hip/hip_runtime.h>
#include <math.h>

#define NN 50000
#define NE 800000
#define D 64
#define TILE 64

typedef __attribute__((ext_vector_type(8))) short short8;
typedef __attribute__((ext_vector_type(4))) float f32x4;

__device__ __forceinline__ float rdlane(float x, int k) {
  return __uint_as_float(__builtin_amdgcn_readlane(__float_as_uint(x), k));
}
__device__ __forceinline__ float silu_f(float x) { return x / (1.0f + __expf(-x)); }
__device__ __forceinline__ float bfly_sum(float x) {
#pragma unroll
  for (int off = 32; off >= 1; off >>= 1) x += __shfl_xor(x, off, 64);
  return x;
}
__device__ __forceinline__ unsigned short f2bf(float f) {
  unsigned int u = __float_as_uint(f);
  u += 0x7fffu + ((u >> 16) & 1u);
  return (unsigned short)(u >> 16);
}
__device__ __forceinline__ unsigned int pack2(float a, float b) {
  return (unsigned int)f2bf(a) | ((unsigned int)f2bf(b) << 16);
}

// ---------------------------------------------------------------------------
// prep (single launch): permute all 5 fp32 weight matrices into bf16 MFMA
// B-fragments. frag(nt,ks): elem(L,j) = W[ks*32 + (L>>4)*8 + j][nt*16 + (L&15)]
// ---------------------------------------------------------------------------
__global__ void prep_all(const float* __restrict__ ng_w2,
                         const float* __restrict__ eg_w1,
                         const float* __restrict__ eg_w2,
                         const float* __restrict__ mg_w1,
                         const float* __restrict__ mg_w2,
                         unsigned short* __restrict__ out) {
  int t = blockIdx.x * 256 + threadIdx.x;
  if (t >= 88 * 64) return;
  int frag = t >> 6, L = t & 63;
  const float* W; int K, N, f0;
  if (frag < 8)       { W = ng_w2; K = 64;  N = 64;  f0 = 0; }
  else if (frag < 16) { W = eg_w1; K = 64;  N = 64;  f0 = 8; }
  else if (frag < 24) { W = eg_w2; K = 64;  N = 64;  f0 = 16; }
  else if (frag < 72) { W = mg_w1; K = 192; N = 128; f0 = 24; }
  else                { W = mg_w2; K = 128; N = 64;  f0 = 72; }
  int lf = frag - f0;
  int kd = K >> 5;
  int nt = lf / kd, ks = lf % kd;
  int kb = ks * 32 + (L >> 4) * 8;
  int nc = nt * 16 + (L & 15);
  unsigned int p[4];
#pragma unroll
  for (int jj = 0; jj < 4; ++jj) {
    float a = W[(size_t)(kb + 2 * jj) * N + nc];
    float b = W[(size_t)(kb + 2 * jj + 1) * N + nc];
    p[jj] = pack2(a, b);
  }
  *(uint4*)(out + (size_t)frag * 512 + L * 8) = make_uint4(p[0], p[1], p[2], p[3]);
}

// ---------------------------------------------------------------------------
// Kernel 1: hoisted first layer of node MLP, 2 nodes per wave
// ---------------------------------------------------------------------------
__global__ void node_pre_kernel(const float* __restrict__ s,
                                const float* __restrict__ ng_w1,
                                const float* __restrict__ ng_b1,
                                float* __restrict__ h_ng) {
  int wave = blockIdx.x * (blockDim.x >> 6) + (threadIdx.x >> 6);
  int d = threadIdx.x & 63;
  int n0 = wave * 2;
  if (n0 >= NN) return;
  float x0 = s[(size_t)n0 * D + d];
  float x1 = (n0 + 1 < NN) ? s[(size_t)(n0 + 1) * D + d] : 0.f;
  float b = ng_b1[d];
  float a0 = b, a1 = b;
#pragma unroll 16
  for (int k = 0; k < D; ++k) {
    float w = ng_w1[k * D + d];
    a0 += rdlane(x0, k) * w;
    a1 += rdlane(x1, k) * w;
  }
  h_ng[(size_t)n0 * D + d] = a0;
  if (n0 + 1 < NN) h_ng[(size_t)(n0 + 1) * D + d] = a1;
}

// ---------------------------------------------------------------------------
// Kernel 2: MFMA edge pipeline. Block = 4 waves, tile = 64 edges.
// LDS regions time-share: region1 holds XE+AE, then A0+A1, then H.
// ---------------------------------------------------------------------------
#define OFF_XE 0
#define OFF_AE 9216
#define OFF_A0 0
#define OFF_A1 9216
#define OFF_H  0
#define OFF_C1 18432
#define OFF_ROW 44032
#define OFF_COL 44288
#define OFF_RIJ 44544
#define OFF_RJI 44800
#define OFF_CMG 45056
#define OFF_U   45312
#define OFF_CP  46080
#define SM_SIZE 47104
#define SA 144
#define SC 400
#define SH 272

__global__ __launch_bounds__(256, 3) void edge_mfma(
    const float* __restrict__ v, const int* __restrict__ ei,
    const float* __restrict__ edge_attr, const float* __restrict__ evu,
    const float* __restrict__ ng_w1, const float* __restrict__ ng_b2,
    const float* __restrict__ eg_w1, const float* __restrict__ eg_b1,
    const float* __restrict__ eg_b2,
    const float* __restrict__ mg_b1, const float* __restrict__ mg_b2,
    const float* __restrict__ pe_w, const float* __restrict__ pe_b,
    const float* __restrict__ h_ng,
    const unsigned short* __restrict__ WF,
    float* __restrict__ s_agg, float* __restrict__ v_agg) {
  __shared__ __align__(16) char sm[SM_SIZE];
  int tid = threadIdx.x;
  int w = tid >> 6, lane = tid & 63, l15 = lane & 15, quad = lane >> 4;
  int edge0 = blockIdx.x * TILE;

  // ---- weight fragments, registers for the whole kernel ----
  short8 F_ng[2], F_e1[2], F_e2[2], F_m1[2][6], F_m2[4];
#pragma unroll
  for (int k = 0; k < 2; ++k) {
    F_ng[k] = *(const short8*)(WF + (size_t)(0 + w * 2 + k) * 512 + lane * 8);
    F_e1[k] = *(const short8*)(WF + (size_t)(8 + w * 2 + k) * 512 + lane * 8);
    F_e2[k] = *(const short8*)(WF + (size_t)(16 + w * 2 + k) * 512 + lane * 8);
  }
#pragma unroll
  for (int n2 = 0; n2 < 2; ++n2)
#pragma unroll
    for (int k = 0; k < 6; ++k)
      F_m1[n2][k] = *(const short8*)(WF + (size_t)(24 + (2 * w + n2) * 6 + k) * 512 + lane * 8);
#pragma unroll
  for (int k = 0; k < 4; ++k)
    F_m2[k] = *(const short8*)(WF + (size_t)(72 + w * 4 + k) * 512 + lane * 8);

  int col = w * 16 + l15;
  float b_ng2 = ng_b2[col];
  float b_e1 = eg_b1[col], b_e2 = eg_b2[col];
  float eglast = eg_w1[64 * 64 + col];
  float b_m1a = mg_b1[w * 32 + l15], b_m1b = mg_b1[w * 32 + 16 + l15];
  float b_m2 = mg_b2[col];
  float pw = pe_w[col];
  float peb = pe_b[0];

  // ---- phase A: per-edge scalars (tid<64)  +  phase B0: stage XE (all) ----
  if (tid < 64) {
    int e = tid, ed = edge0 + e;
    int r = ei[ed], c = ei[NE + ed];
    float u0 = evu[ed * 3 + 0], u1 = evu[ed * 3 + 1], u2 = evu[ed * 3 + 2];
    float vi0 = v[r * 3 + 0], vi1 = v[r * 3 + 1], vi2 = v[r * 3 + 2];
    float vj0 = v[c * 3 + 0], vj1 = v[c * 3 + 1], vj2 = v[c * 3 + 2];
    ((int*)(sm + OFF_ROW))[e] = r;
    ((int*)(sm + OFF_COL))[e] = c;
    ((float*)(sm + OFF_RIJ))[e] = 1.0f - (vi0 * u0 + vi1 * u1 + vi2 * u2);
    ((float*)(sm + OFF_RJI))[e] = 1.0f + (vj0 * u0 + vj1 * u1 + vj2 * u2);
    float cx = vi1 * vj2 - vi2 * vj1;
    float cy = vi2 * vj0 - vi0 * vj2;
    float cz = vi0 * vj1 - vi1 * vj0;
    ((float*)(sm + OFF_CMG))[e] = sqrtf(cx * cx + cy * cy + cz * cz);
    ((float*)(sm + OFF_U))[e * 3 + 0] = u0;
    ((float*)(sm + OFF_U))[e * 3 + 1] = u1;
    ((float*)(sm + OFF_U))[e * 3 + 2] = u2;
  }
  {
    int e = tid >> 2, fq = (tid & 3) * 16;
    float va[16];
#pragma unroll
    for (int q = 0; q < 4; ++q) {
      f32x4 x = *(const f32x4*)(edge_attr + (size_t)(edge0 + e) * D + fq + q * 4);
#pragma unroll
      for (int c2 = 0; c2 < 4; ++c2) va[q * 4 + c2] = x[c2];
    }
    *(uint4*)(sm + OFF_XE + e * SA + fq * 2) =
        make_uint4(pack2(va[0], va[1]), pack2(va[2], va[3]), pack2(va[4], va[5]), pack2(va[6], va[7]));
    *(uint4*)(sm + OFF_XE + e * SA + fq * 2 + 16) =
        make_uint4(pack2(va[8], va[9]), pack2(va[10], va[11]), pack2(va[12], va[13]), pack2(va[14], va[15]));
  }
  __syncthreads();

  // ---- ae = silu(XE @ eg_w1 + b + cmag*w_last) -> AE ----
#pragma unroll
  for (int mt = 0; mt < 4; ++mt) {
    f32x4 acc = {0.f, 0.f, 0.f, 0.f};
    short8 a0 = *(const short8*)(sm + OFF_XE + (mt * 16 + l15) * SA + quad * 16);
    short8 a1 = *(const short8*)(sm + OFF_XE + (mt * 16 + l15) * SA + 64 + quad * 16);
    acc = __builtin_amdgcn_mfma_f32_16x16x32_bf16(a0, F_e1[0], acc, 0, 0, 0);
    acc = __builtin_amdgcn_mfma_f32_16x16x32_bf16(a1, F_e1[1], acc, 0, 0, 0);
    int e0 = mt * 16 + quad * 4;
#pragma unroll
    for (int r = 0; r < 4; ++r) {
      float cm = ((const float*)(sm + OFF_CMG))[e0 + r];
      *(unsigned short*)(sm + OFF_AE + (e0 + r) * SA + col * 2) =
          f2bf(silu_f(acc[r] + b_e1 + cm * eglast));
    }
  }
  __syncthreads();

  // ---- ef = AE @ eg_w2 + b -> C1 cols [128,192) ----
#pragma unroll
  for (int mt = 0; mt < 4; ++mt) {
    f32x4 acc = {0.f, 0.f, 0.f, 0.f};
    short8 a0 = *(const short8*)(sm + OFF_AE + (mt * 16 + l15) * SA + quad * 16);
    short8 a1 = *(const short8*)(sm + OFF_AE + (mt * 16 + l15) * SA + 64 + quad * 16);
    acc = __builtin_amdgcn_mfma_f32_16x16x32_bf16(a0, F_e2[0], acc, 0, 0, 0);
    acc = __builtin_amdgcn_mfma_f32_16x16x32_bf16(a1, F_e2[1], acc, 0, 0, 0);
    int e0 = mt * 16 + quad * 4;
#pragma unroll
    for (int r = 0; r < 4; ++r)
      *(unsigned short*)(sm + OFF_C1 + (e0 + r) * SC + (128 + col) * 2) = f2bf(acc[r] + b_e2);
  }
  __syncthreads();

  // ---- phase B1: stage A0 (a_i), A1 (a_j) over XE/AE space ----
  {
    int e = tid >> 2, fq = (tid & 3) * 16;
    int rr = ((const int*)(sm + OFF_ROW))[e];
    int cc = ((const int*)(sm + OFF_COL))[e];
    float rij = ((const float*)(sm + OFF_RIJ))[e];
    float rji = ((const float*)(sm + OFF_RJI))[e];
    f32x4 wl[4];
#pragma unroll
    for (int q = 0; q < 4; ++q) wl[q] = *(const f32x4*)(ng_w1 + 64 * 64 + fq + q * 4);

    float va[16];
#pragma unroll
    for (int q = 0; q < 4; ++q) {
      f32x4 h = *(const f32x4*)(h_ng + (size_t)rr * D + fq + q * 4);
#pragma unroll
      for (int c2 = 0; c2 < 4; ++c2) va[q * 4 + c2] = silu_f(h[c2] + rij * wl[q][c2]);
    }
    *(uint4*)(sm + OFF_A0 + e * SA + fq * 2) =
        make_uint4(pack2(va[0], va[1]), pack2(va[2], va[3]), pack2(va[4], va[5]), pack2(va[6], va[7]));
    *(uint4*)(sm + OFF_A0 + e * SA + fq * 2 + 16) =
        make_uint4(pack2(va[8], va[9]), pack2(va[10], va[11]), pack2(va[12], va[13]), pack2(va[14], va[15]));

#pragma unroll
    for (int q = 0; q < 4; ++q) {
      f32x4 h = *(const f32x4*)(h_ng + (size_t)cc * D + fq + q * 4);
#pragma unroll
      for (int c2 = 0; c2 < 4; ++c2) va[q * 4 + c2] = silu_f(h[c2] + rji * wl[q][c2]);
    }
    *(uint4*)(sm + OFF_A1 + e * SA + fq * 2) =
        make_uint4(pack2(va[0], va[1]), pack2(va[2], va[3]), pack2(va[4], va[5]), pack2(va[6], va[7]));
    *(uint4*)(sm + OFF_A1 + e * SA + fq * 2 + 16) =
        make_uint4(pack2(va[8], va[9]), pack2(va[10], va[11]), pack2(va[12], va[13]), pack2(va[14], va[15]));
  }
  __syncthreads();

  // ---- nf_i -> C1 cols [0,64), nf_j -> C1 cols [64,128) ----
#pragma unroll
  for (int mt = 0; mt < 4; ++mt) {
    f32x4 acc = {0.f, 0.f, 0.f, 0.f};
    short8 a0 = *(const short8*)(sm + OFF_A0 + (mt * 16 + l15) * SA + quad * 16);
    short8 a1 = *(const short8*)(sm + OFF_A0 + (mt * 16 + l15) * SA + 64 + quad * 16);
    acc = __builtin_amdgcn_mfma_f32_16x16x32_bf16(a0, F_ng[0], acc, 0, 0, 0);
    acc = __builtin_amdgcn_mfma_f32_16x16x32_bf16(a1, F_ng[1], acc, 0, 0, 0);
    int e0 = mt * 16 + quad * 4;
#pragma unroll
    for (int r = 0; r < 4; ++r)
      *(unsigned short*)(sm + OFF_C1 + (e0 + r) * SC + col * 2) = f2bf(acc[r] + b_ng2);
  }
#pragma unroll
  for (int mt = 0; mt < 4; ++mt) {
    f32x4 acc = {0.f, 0.f, 0.f, 0.f};
    short8 a0 = *(const short8*)(sm + OFF_A1 + (mt * 16 + l15) * SA + quad * 16);
    short8 a1 = *(const short8*)(sm + OFF_A1 + (mt * 16 + l15) * SA + 64 + quad * 16);
    acc = __builtin_amdgcn_mfma_f32_16x16x32_bf16(a0, F_ng[0], acc, 0, 0, 0);
    acc = __builtin_amdgcn_mfma_f32_16x16x32_bf16(a1, F_ng[1], acc, 0, 0, 0);
    int e0 = mt * 16 + quad * 4;
#pragma unroll
    for (int r = 0; r < 4; ++r)
      *(unsigned short*)(sm + OFF_C1 + (e0 + r) * SC + (64 + col) * 2) = f2bf(acc[r] + b_ng2);
  }
  __syncthreads();

  // ---- h1 = silu(C1[64x192] @ mg_w1 + b) -> H over A0/A1 space ----
#pragma unroll
  for (int mt = 0; mt < 4; ++mt) {
    f32x4 acc0 = {0.f, 0.f, 0.f, 0.f};
    f32x4 acc1 = {0.f, 0.f, 0.f, 0.f};
#pragma unroll
    for (int ks = 0; ks < 6; ++ks) {
      short8 a = *(const short8*)(sm + OFF_C1 + (mt * 16 + l15) * SC + ks * 64 + quad * 16);
      acc0 = __builtin_amdgcn_mfma_f32_16x16x32_bf16(a, F_m1[0][ks], acc0, 0, 0, 0);
      acc1 = __builtin_amdgcn_mfma_f32_16x16x32_bf16(a, F_m1[1][ks], acc1, 0, 0, 0);
    }
    int e0 = mt * 16 + quad * 4;
    int ca = w * 32 + l15, cb = w * 32 + 16 + l15;
#pragma unroll
    for (int r = 0; r < 4; ++r) {
      *(unsigned short*)(sm + OFF_H + (e0 + r) * SH + ca * 2) = f2bf(silu_f(acc0[r] + b_m1a));
      *(unsigned short*)(sm + OFF_H + (e0 + r) * SH + cb * 2) = f2bf(silu_f(acc1[r] + b_m1b));
    }
  }
  __syncthreads();

  // ---- msg = H @ mg_w2 + b ; coeff partials ; scatter s_agg ----
#pragma unroll
  for (int mt = 0; mt < 4; ++mt) {
    f32x4 acc = {0.f, 0.f, 0.f, 0.f};
#pragma unroll
    for (int ks = 0; ks < 4; ++ks) {
      short8 a = *(const short8*)(sm + OFF_H + (mt * 16 + l15) * SH + ks * 64 + quad * 16);
      acc = __builtin_amdgcn_mfma_f32_16x16x32_bf16(a, F_m2[ks], acc, 0, 0, 0);
    }
    int e0 = mt * 16 + quad * 4;
#pragma unroll
    for (int r = 0; r < 4; ++r) {
      float m = acc[r] + b_m2;
      float p = m * pw;
      p += __shfl_xor(p, 1, 64);
      p += __shfl_xor(p, 2, 64);
      p += __shfl_xor(p, 4, 64);
      p += __shfl_xor(p, 8, 64);
      if (l15 == 0) ((float*)(sm + OFF_CP))[(e0 + r) * 4 + w] = p;
      int rn = ((const int*)(sm + OFF_ROW))[e0 + r];
      atomicAdd(&s_agg[(size_t)rn * D + col], m);
    }
  }
  __syncthreads();

  // ---- v_agg scatter ----
  if (tid < 64) {
    const float* cp = (const float*)(sm + OFF_CP);
    float c = cp[tid * 4] + cp[tid * 4 + 1] + cp[tid * 4 + 2] + cp[tid * 4 + 3] + peb;
    int rn = ((const int*)(sm + OFF_ROW))[tid];
    const float* uu = (const float*)(sm + OFF_U);
    atomicAdd(&v_agg[rn * 3 + 0], uu[tid * 3 + 0] * c);
    atomicAdd(&v_agg[rn * 3 + 1], uu[tid * 3 + 1] * c);
    atomicAdd(&v_agg[rn * 3 + 2], uu[tid * 3 + 2] * c);
  }
}

// ---------------------------------------------------------------------------
// Kernel 3: node update + layernorm + v normalize, 2 nodes per wave
// ---------------------------------------------------------------------------
__global__ void node_out_kernel(
    const float* __restrict__ s, const float* __restrict__ v,
    const float* __restrict__ up_w, const float* __restrict__ up_b,
    const float* __restrict__ ln_g, const float* __restrict__ ln_b,
    const float* __restrict__ s_agg, const float* __restrict__ v_agg,
    float* __restrict__ out) {
  int wave = blockIdx.x * (blockDim.x >> 6) + (threadIdx.x >> 6);
  int d = threadIdx.x & 63;
  int n0 = wave * 2;
  if (n0 >= NN) return;
  bool two = (n0 + 1 < NN);

  float g0 = silu_f(s_agg[(size_t)n0 * D + d]);
  float g1 = two ? silu_f(s_agg[(size_t)(n0 + 1) * D + d]) : 0.f;
  float ub = up_b[d];
  float a0 = ub, a1 = ub;
#pragma unroll 16
  for (int k = 0; k < D; ++k) {
    float wv = up_w[k * D + d];
    a0 += rdlane(g0, k) * wv;
    a1 += rdlane(g1, k) * wv;
  }
  float lg = ln_g[d], lb = ln_b[d];
#pragma unroll
  for (int jj = 0; jj < 2; ++jj) {
    int n = n0 + jj;
    if (jj && !two) break;
    float s_new = s[(size_t)n * D + d] + (jj ? a1 : a0);
    float mu = bfly_sum(s_new) * (1.0f / 64.0f);
    float diff = s_new - mu;
    float var = bfly_sum(diff * diff) * (1.0f / 64.0f);
    float inv = 1.0f / sqrtf(var + 1e-5f);
    out[(size_t)n * D + d] = diff * inv * lg + lb;
    if (d < 3) {
      float v0 = v[n * 3 + 0] + v_agg[(size_t)n * 3 + 0];
      float v1 = v[n * 3 + 1] + v_agg[(size_t)n * 3 + 1];
      float v2 = v[n * 3 + 2] + v_agg[(size_t)n * 3 + 2];
      float nrm = sqrtf(v0 * v0 + v1 * v1 + v2 * v2);
      float denom = fmaxf(nrm, 1e-6f);
      float val = (d == 0) ? v0 : ((d == 1) ? v1 : v2);
      out[(size_t)NN * D + (size_t)n * 3 + d] = val / denom;
    }
  }
}

// ---------------------------------------------------------------------------
extern "C" void kernel_launch(void* const* d_in, const int* in_sizes, int n_in,
                              void* d_out, int out_size, void* d_ws, size_t ws_size,
                              hipStream_t stream) {
  const float* s         = (const float*)d_in[0];
  const float* v         = (const float*)d_in[1];
  const int*   ei        = (const int*)d_in[2];
  const float* edge_attr = (const float*)d_in[3];
  const float* evu       = (const float*)d_in[4];
  const float* ng_w1     = (const float*)d_in[5];
  const float* ng_b1     = (const float*)d_in[6];
  const float* ng_w2     = (const float*)d_in[7];
  const float* ng_b2     = (const float*)d_in[8];
  const float* eg_w1     = (const float*)d_in[9];
  const float* eg_b1     = (const float*)d_in[10];
  const float* eg_w2     = (const float*)d_in[11];
  const float* eg_b2     = (const float*)d_in[12];
  const float* mg_w1     = (const float*)d_in[13];
  const float* mg_b1     = (const float*)d_in[14];
  const float* mg_w2     = (const float*)d_in[15];
  const float* mg_b2     = (const float*)d_in[16];
  const float* pe_w      = (const float*)d_in[17];
  const float* pe_b      = (const float*)d_in[18];
  const float* up_w      = (const float*)d_in[19];
  const float* up_b      = (const float*)d_in[20];
  const float* ln_g      = (const float*)d_in[21];
  const float* ln_b      = (const float*)d_in[22];
  (void)in_sizes; (void)n_in; (void)out_size; (void)ws_size;

  float* out   = (float*)d_out;
  float* s_agg = (float*)d_ws;                            // NN*64 floats
  float* v_agg = s_agg + (size_t)NN * D;                  // NN*3 floats
  unsigned short* WF = (unsigned short*)(v_agg + (size_t)NN * 3);  // 88 frags * 512 bf16
  float* h_ng  = out;  // reuse d_out as scratch for hoisted node-MLP layer

  hipMemsetAsync(d_ws, 0, (size_t)(NN * D + NN * 3) * sizeof(float), stream);

  prep_all<<<22, 256, 0, stream>>>(ng_w2, eg_w1, eg_w2, mg_w1, mg_w2, WF);

  // 25000 waves (2 nodes each), 4 waves/block
  node_pre_kernel<<<(25000 + 3) / 4, 256, 0, stream>>>(s, ng_w1, ng_b1, h_ng);

  edge_mfma<<<NE / TILE, 256, 0, stream>>>(
      v, ei, edge_attr, evu,
      ng_w1, ng_b2, eg_w1, eg_b1, eg_b2,
      mg_b1, mg_b2, pe_w, pe_b, h_ng, WF, s_agg, v_agg);

  node_out_kernel<<<(25000 + 3) / 4, 256, 0, stream>>>(
      s, v, up_w, up_b, ln_g, ln_b, s_agg, v_agg, out);
}

// Round 4
// 587.257 us; speedup vs baseline: 4.8260x; 1.1827x over previous
//
#include <hip/hip_runtime.h>
#include <math.h>

#define NN 50000
#define NE 800000
#define D 64

typedef __attribute__((ext_vector_type(8))) short short8;
typedef __attribute__((ext_vector_type(4))) float f32x4;

__device__ __forceinline__ float silu_f(float x) { return x / (1.0f + __expf(-x)); }
__device__ __forceinline__ unsigned short f2bf(float f) {
  unsigned int u = __float_as_uint(f);
  u += 0x7fffu + ((u >> 16) & 1u);
  return (unsigned short)(u >> 16);
}
__device__ __forceinline__ unsigned int pack2(float a, float b) {
  return (unsigned int)f2bf(a) | ((unsigned int)f2bf(b) << 16);
}
__device__ __forceinline__ short8 pack_frag(f32x4 a, f32x4 b) {
  union { unsigned int u[4]; short8 s; } r;
  r.u[0] = pack2(a[0], a[1]);
  r.u[1] = pack2(a[2], a[3]);
  r.u[2] = pack2(b[0], b[1]);
  r.u[3] = pack2(b[2], b[3]);
  return r.s;
}

// ---------------------------------------------------------------------------
// prep: permute fp32 weights into bf16 MFMA fragments.
// frag(nt,ks): elem(L,j) = W[ks*32 + (L>>4)*8 + j][nt*16 + (L&15)]
// (this is simultaneously the B-layout for X@W and the A-layout for W^T@X^T)
// ---------------------------------------------------------------------------
__global__ void prep_all(const float* __restrict__ ng_w2,
                         const float* __restrict__ eg_w1,
                         const float* __restrict__ eg_w2,
                         const float* __restrict__ mg_w1,
                         const float* __restrict__ mg_w2,
                         const float* __restrict__ ng_w1,
                         const float* __restrict__ up_w,
                         unsigned short* __restrict__ out) {
  int t = blockIdx.x * 256 + threadIdx.x;
  if (t >= 104 * 64) return;
  int frag = t >> 6, L = t & 63;
  const float* W; int K, N, f0;
  if (frag < 8)       { W = ng_w2; K = 64;  N = 64;  f0 = 0; }
  else if (frag < 16) { W = eg_w1; K = 64;  N = 64;  f0 = 8; }
  else if (frag < 24) { W = eg_w2; K = 64;  N = 64;  f0 = 16; }
  else if (frag < 72) { W = mg_w1; K = 192; N = 128; f0 = 24; }
  else if (frag < 88) { W = mg_w2; K = 128; N = 64;  f0 = 72; }
  else if (frag < 96) { W = ng_w1; K = 64;  N = 64;  f0 = 88; }
  else                { W = up_w;  K = 64;  N = 64;  f0 = 96; }
  int lf = frag - f0;
  int kd = K >> 5;
  int nt = lf / kd, ks = lf % kd;
  int kb = ks * 32 + (L >> 4) * 8;
  int nc = nt * 16 + (L & 15);
  unsigned int p[4];
#pragma unroll
  for (int jj = 0; jj < 4; ++jj) {
    float a = W[(size_t)(kb + 2 * jj) * N + nc];
    float b = W[(size_t)(kb + 2 * jj + 1) * N + nc];
    p[jj] = pack2(a, b);
  }
  *(uint4*)(out + (size_t)frag * 512 + L * 8) = make_uint4(p[0], p[1], p[2], p[3]);
}

// ---------------------------------------------------------------------------
// node_pre: h_ng = s @ ng_w1[0:64] + b1, MFMA, 32 nodes/wave, barrier-free.
// ---------------------------------------------------------------------------
__global__ __launch_bounds__(256, 4) void node_pre(
    const float* __restrict__ s, const float* __restrict__ ng_b1,
    const unsigned short* __restrict__ WF, float* __restrict__ h_ng) {
  __shared__ __align__(16) char sm[4 * 8704];
  int tid = threadIdx.x, w = tid >> 6, lane = tid & 63;
  int l15 = lane & 15, q = lane >> 4, fb = q * 8;
  char* my = sm + w * 8704;
  int nb = (blockIdx.x * 4 + w) * 32;
  if (nb >= NN) return;

  short8 Bs[2][2];
#pragma unroll
  for (int h = 0; h < 2; ++h)
#pragma unroll
    for (int kt = 0; kt < 2; ++kt) {
      int n = nb + h * 16 + l15; if (n >= NN) n = NN - 1;
      f32x4 x0 = *(const f32x4*)(s + (size_t)n * D + kt * 32 + fb);
      f32x4 x1 = *(const f32x4*)(s + (size_t)n * D + kt * 32 + fb + 4);
      Bs[h][kt] = pack_frag(x0, x1);
    }
  short8 F[4][2]; f32x4 bb[4];
#pragma unroll
  for (int mt = 0; mt < 4; ++mt) {
    F[mt][0] = *(const short8*)(WF + (size_t)(88 + mt * 2 + 0) * 512 + lane * 8);
    F[mt][1] = *(const short8*)(WF + (size_t)(88 + mt * 2 + 1) * 512 + lane * 8);
    bb[mt] = *(const f32x4*)(ng_b1 + mt * 16 + 4 * q);
  }
#pragma unroll
  for (int h = 0; h < 2; ++h)
#pragma unroll
    for (int mt = 0; mt < 4; ++mt) {
      f32x4 acc = {0.f, 0.f, 0.f, 0.f};
      acc = __builtin_amdgcn_mfma_f32_16x16x32_bf16(F[mt][0], Bs[h][0], acc, 0, 0, 0);
      acc = __builtin_amdgcn_mfma_f32_16x16x32_bf16(F[mt][1], Bs[h][1], acc, 0, 0, 0);
      acc[0] += bb[mt][0]; acc[1] += bb[mt][1]; acc[2] += bb[mt][2]; acc[3] += bb[mt][3];
      *(f32x4*)(my + (((h * 16 + l15) * 68 + mt * 16 + 4 * q) << 2)) = acc;
    }
#pragma unroll
  for (int h = 0; h < 2; ++h)
#pragma unroll
    for (int e = 0; e < 16; ++e) {
      int n = nb + h * 16 + e;
      if (n < NN) {
        float val = *(const float*)(my + (((h * 16 + e) * 68 + lane) << 2));
        h_ng[(size_t)n * D + lane] = val;
      }
    }
}

// ---------------------------------------------------------------------------
// edge_mfma: full edge pipeline, 32 edges/wave, zero __syncthreads.
// Wave-private LDS slice: 32 rows x 104 dw (bf16 activations / f32 msg).
// ---------------------------------------------------------------------------
#define LSTR 104
#define LDSW (32 * LSTR * 4)

__global__ __launch_bounds__(256, 3) void edge_mfma(
    const float* __restrict__ v, const int* __restrict__ ei,
    const float* __restrict__ edge_attr, const float* __restrict__ evu,
    const float* __restrict__ ng_w1, const float* __restrict__ ng_b2,
    const float* __restrict__ eg_w1, const float* __restrict__ eg_b1,
    const float* __restrict__ eg_b2,
    const float* __restrict__ mg_b1, const float* __restrict__ mg_b2,
    const float* __restrict__ pe_w, const float* __restrict__ pe_b,
    const float* __restrict__ h_ng,
    const unsigned short* __restrict__ WF,
    float* __restrict__ s_agg, float* __restrict__ v_agg) {
  __shared__ __align__(16) char sm[4 * LDSW];
  int tid = threadIdx.x, w = tid >> 6, lane = tid & 63;
  int l15 = lane & 15, q = lane >> 4, fb = q * 8;
  char* my = sm + w * LDSW;
  int eb = (blockIdx.x * 4 + w) * 32;

  // ---- per-edge scalars (redundant across quads; lane's edge = eb+h*16+l15)
  int rown[2], coln[2];
  float rij[2], rji[2], uu0[2], uu1[2], uu2[2], cmag[2];
#pragma unroll
  for (int h = 0; h < 2; ++h) {
    int e = eb + h * 16 + l15;
    int r = ei[e], c = ei[NE + e];
    rown[h] = r; coln[h] = c;
    float u0 = evu[e * 3 + 0], u1 = evu[e * 3 + 1], u2 = evu[e * 3 + 2];
    uu0[h] = u0; uu1[h] = u1; uu2[h] = u2;
    float vi0 = v[r * 3 + 0], vi1 = v[r * 3 + 1], vi2 = v[r * 3 + 2];
    float vj0 = v[c * 3 + 0], vj1 = v[c * 3 + 1], vj2 = v[c * 3 + 2];
    rij[h] = 1.f - (vi0 * u0 + vi1 * u1 + vi2 * u2);
    rji[h] = 1.f + (vj0 * u0 + vj1 * u1 + vj2 * u2);
    float cx = vi1 * vj2 - vi2 * vj1;
    float cy = vi2 * vj0 - vi0 * vj2;
    float cz = vi0 * vj1 - vi1 * vj0;
    cmag[h] = sqrtf(cx * cx + cy * cy + cz * cz);
  }

  // ---- stage B-frags: a_i, a_j (silu of hoisted layer + res*w1last), Xe
  short8 Bai[2][2], Baj[2][2], Bxe[2][2];
  f32x4 w1l[2][2];
#pragma unroll
  for (int kt = 0; kt < 2; ++kt) {
    w1l[kt][0] = *(const f32x4*)(ng_w1 + 64 * 64 + kt * 32 + fb);
    w1l[kt][1] = *(const f32x4*)(ng_w1 + 64 * 64 + kt * 32 + fb + 4);
  }
#pragma unroll
  for (int h = 0; h < 2; ++h)
#pragma unroll
    for (int kt = 0; kt < 2; ++kt) {
      const float* pr = h_ng + (size_t)rown[h] * D + kt * 32 + fb;
      const float* pc = h_ng + (size_t)coln[h] * D + kt * 32 + fb;
      const float* px = edge_attr + (size_t)(eb + h * 16 + l15) * D + kt * 32 + fb;
      f32x4 a0 = *(const f32x4*)pr, a1 = *(const f32x4*)(pr + 4);
      f32x4 b0 = *(const f32x4*)pc, b1 = *(const f32x4*)(pc + 4);
      f32x4 x0 = *(const f32x4*)px, x1 = *(const f32x4*)(px + 4);
      f32x4 si0, si1, sj0, sj1;
#pragma unroll
      for (int c2 = 0; c2 < 4; ++c2) {
        si0[c2] = silu_f(a0[c2] + rij[h] * w1l[kt][0][c2]);
        si1[c2] = silu_f(a1[c2] + rij[h] * w1l[kt][1][c2]);
        sj0[c2] = silu_f(b0[c2] + rji[h] * w1l[kt][0][c2]);
        sj1[c2] = silu_f(b1[c2] + rji[h] * w1l[kt][1][c2]);
      }
      Bai[h][kt] = pack_frag(si0, si1);
      Baj[h][kt] = pack_frag(sj0, sj1);
      Bxe[h][kt] = pack_frag(x0, x1);
    }

  // ---- nf_i (feats->fdw 0..31), nf_j (fdw 32..63): D^T = ng_w2^T @ a^T
  {
    short8 F[4][2]; f32x4 bb[4];
#pragma unroll
    for (int mt = 0; mt < 4; ++mt) {
      F[mt][0] = *(const short8*)(WF + (size_t)(0 + mt * 2 + 0) * 512 + lane * 8);
      F[mt][1] = *(const short8*)(WF + (size_t)(0 + mt * 2 + 1) * 512 + lane * 8);
      bb[mt] = *(const f32x4*)(ng_b2 + mt * 16 + 4 * q);
    }
#pragma unroll
    for (int h = 0; h < 2; ++h)
#pragma unroll
      for (int mt = 0; mt < 4; ++mt) {
        f32x4 ai = {0.f, 0.f, 0.f, 0.f}, aj = {0.f, 0.f, 0.f, 0.f};
        ai = __builtin_amdgcn_mfma_f32_16x16x32_bf16(F[mt][0], Bai[h][0], ai, 0, 0, 0);
        ai = __builtin_amdgcn_mfma_f32_16x16x32_bf16(F[mt][1], Bai[h][1], ai, 0, 0, 0);
        aj = __builtin_amdgcn_mfma_f32_16x16x32_bf16(F[mt][0], Baj[h][0], aj, 0, 0, 0);
        aj = __builtin_amdgcn_mfma_f32_16x16x32_bf16(F[mt][1], Baj[h][1], aj, 0, 0, 0);
        uint2 pi, pj;
        pi.x = pack2(ai[0] + bb[mt][0], ai[1] + bb[mt][1]);
        pi.y = pack2(ai[2] + bb[mt][2], ai[3] + bb[mt][3]);
        pj.x = pack2(aj[0] + bb[mt][0], aj[1] + bb[mt][1]);
        pj.y = pack2(aj[2] + bb[mt][2], aj[3] + bb[mt][3]);
        int row = h * 16 + l15;
        *(uint2*)(my + ((row * LSTR + mt * 8 + 2 * q) << 2)) = pi;
        *(uint2*)(my + ((row * LSTR + 32 + mt * 8 + 2 * q) << 2)) = pj;
      }
  }

  // ---- ae = silu(Xe @ eg_w1 + b + cmag*w_last)  -> fdw 64..95
  {
    short8 F[4][2]; f32x4 bb[4], el[4];
#pragma unroll
    for (int mt = 0; mt < 4; ++mt) {
      F[mt][0] = *(const short8*)(WF + (size_t)(8 + mt * 2 + 0) * 512 + lane * 8);
      F[mt][1] = *(const short8*)(WF + (size_t)(8 + mt * 2 + 1) * 512 + lane * 8);
      bb[mt] = *(const f32x4*)(eg_b1 + mt * 16 + 4 * q);
      el[mt] = *(const f32x4*)(eg_w1 + 64 * 64 + mt * 16 + 4 * q);
    }
#pragma unroll
    for (int h = 0; h < 2; ++h)
#pragma unroll
      for (int mt = 0; mt < 4; ++mt) {
        f32x4 acc = {0.f, 0.f, 0.f, 0.f};
        acc = __builtin_amdgcn_mfma_f32_16x16x32_bf16(F[mt][0], Bxe[h][0], acc, 0, 0, 0);
        acc = __builtin_amdgcn_mfma_f32_16x16x32_bf16(F[mt][1], Bxe[h][1], acc, 0, 0, 0);
        float t0 = silu_f(acc[0] + bb[mt][0] + cmag[h] * el[mt][0]);
        float t1 = silu_f(acc[1] + bb[mt][1] + cmag[h] * el[mt][1]);
        float t2 = silu_f(acc[2] + bb[mt][2] + cmag[h] * el[mt][2]);
        float t3 = silu_f(acc[3] + bb[mt][3] + cmag[h] * el[mt][3]);
        uint2 p; p.x = pack2(t0, t1); p.y = pack2(t2, t3);
        *(uint2*)(my + (((h * 16 + l15) * LSTR + 64 + mt * 8 + 2 * q) << 2)) = p;
      }
  }

  // ---- ef = ae @ eg_w2 + b  (read ae B-frags, overwrite fdw 64..95)
  {
    short8 Bae[2][2];
#pragma unroll
    for (int h = 0; h < 2; ++h)
#pragma unroll
      for (int kt = 0; kt < 2; ++kt)
        Bae[h][kt] = *(const short8*)(my + (((h * 16 + l15) * LSTR + 64 + 16 * kt + 4 * q) << 2));
    short8 F[4][2]; f32x4 bb[4];
#pragma unroll
    for (int mt = 0; mt < 4; ++mt) {
      F[mt][0] = *(const short8*)(WF + (size_t)(16 + mt * 2 + 0) * 512 + lane * 8);
      F[mt][1] = *(const short8*)(WF + (size_t)(16 + mt * 2 + 1) * 512 + lane * 8);
      bb[mt] = *(const f32x4*)(eg_b2 + mt * 16 + 4 * q);
    }
#pragma unroll
    for (int h = 0; h < 2; ++h)
#pragma unroll
      for (int mt = 0; mt < 4; ++mt) {
        f32x4 acc = {0.f, 0.f, 0.f, 0.f};
        acc = __builtin_amdgcn_mfma_f32_16x16x32_bf16(F[mt][0], Bae[h][0], acc, 0, 0, 0);
        acc = __builtin_amdgcn_mfma_f32_16x16x32_bf16(F[mt][1], Bae[h][1], acc, 0, 0, 0);
        uint2 p;
        p.x = pack2(acc[0] + bb[mt][0], acc[1] + bb[mt][1]);
        p.y = pack2(acc[2] + bb[mt][2], acc[3] + bb[mt][3]);
        *(uint2*)(my + (((h * 16 + l15) * LSTR + 64 + mt * 8 + 2 * q) << 2)) = p;
      }
  }

  // ---- h1 = silu([nfi|nfj|ef] @ mg_w1 + b): read 6 k-tiles, write fdw 0..63
  {
    short8 Bin[2][6];
#pragma unroll
    for (int h = 0; h < 2; ++h)
#pragma unroll
      for (int kt = 0; kt < 6; ++kt)
        Bin[h][kt] = *(const short8*)(my + (((h * 16 + l15) * LSTR + 16 * kt + 4 * q) << 2));
#pragma unroll
    for (int mt = 0; mt < 8; ++mt) {
      short8 F[6];
#pragma unroll
      for (int ks = 0; ks < 6; ++ks)
        F[ks] = *(const short8*)(WF + (size_t)(24 + mt * 6 + ks) * 512 + lane * 8);
      f32x4 bb = *(const f32x4*)(mg_b1 + mt * 16 + 4 * q);
#pragma unroll
      for (int h = 0; h < 2; ++h) {
        f32x4 acc = {0.f, 0.f, 0.f, 0.f};
#pragma unroll
        for (int ks = 0; ks < 6; ++ks)
          acc = __builtin_amdgcn_mfma_f32_16x16x32_bf16(F[ks], Bin[h][ks], acc, 0, 0, 0);
        uint2 p;
        p.x = pack2(silu_f(acc[0] + bb[0]), silu_f(acc[1] + bb[1]));
        p.y = pack2(silu_f(acc[2] + bb[2]), silu_f(acc[3] + bb[3]));
        *(uint2*)(my + (((h * 16 + l15) * LSTR + mt * 8 + 2 * q) << 2)) = p;
      }
    }
  }

  // ---- msg = h1 @ mg_w2 + b  (read 4 k-tiles)
  f32x4 msg[2][4];
  {
    short8 Bh[2][4];
#pragma unroll
    for (int h = 0; h < 2; ++h)
#pragma unroll
      for (int kt = 0; kt < 4; ++kt)
        Bh[h][kt] = *(const short8*)(my + (((h * 16 + l15) * LSTR + 16 * kt + 4 * q) << 2));
#pragma unroll
    for (int mt = 0; mt < 4; ++mt) {
      short8 F[4];
#pragma unroll
      for (int ks = 0; ks < 4; ++ks)
        F[ks] = *(const short8*)(WF + (size_t)(72 + mt * 4 + ks) * 512 + lane * 8);
      f32x4 bb = *(const f32x4*)(mg_b2 + mt * 16 + 4 * q);
#pragma unroll
      for (int h = 0; h < 2; ++h) {
        f32x4 acc = {0.f, 0.f, 0.f, 0.f};
#pragma unroll
        for (int ks = 0; ks < 4; ++ks)
          acc = __builtin_amdgcn_mfma_f32_16x16x32_bf16(F[ks], Bh[h][ks], acc, 0, 0, 0);
        acc[0] += bb[0]; acc[1] += bb[1]; acc[2] += bb[2]; acc[3] += bb[3];
        msg[h][mt] = acc;
      }
    }
  }

  // ---- coeff (reduce over quads), v_agg scatter
  float part[2] = {0.f, 0.f};
#pragma unroll
  for (int mt = 0; mt < 4; ++mt) {
    f32x4 pw4 = *(const f32x4*)(pe_w + mt * 16 + 4 * q);
#pragma unroll
    for (int h = 0; h < 2; ++h)
      part[h] += msg[h][mt][0] * pw4[0] + msg[h][mt][1] * pw4[1] +
                 msg[h][mt][2] * pw4[2] + msg[h][mt][3] * pw4[3];
  }
  float peb = pe_b[0];
#pragma unroll
  for (int h = 0; h < 2; ++h) {
    part[h] += __shfl_xor(part[h], 16, 64);
    part[h] += __shfl_xor(part[h], 32, 64);
    if (q < 3) {
      float uc = (q == 0) ? uu0[h] : ((q == 1) ? uu1[h] : uu2[h]);
      atomicAdd(&v_agg[(size_t)rown[h] * 3 + q], uc * (part[h] + peb));
    }
  }

  // ---- msg f32 -> LDS (overwrite fdw 0..63), coalesced atomic scatter
#pragma unroll
  for (int h = 0; h < 2; ++h)
#pragma unroll
    for (int mt = 0; mt < 4; ++mt)
      *(f32x4*)(my + (((h * 16 + l15) * LSTR + mt * 16 + 4 * q) << 2)) = msg[h][mt];
#pragma unroll
  for (int h = 0; h < 2; ++h)
#pragma unroll
    for (int e = 0; e < 16; ++e) {
      int sr = __builtin_amdgcn_readlane(rown[h], e);
      float val = *(const float*)(my + (((h * 16 + e) * LSTR + lane) << 2));
      atomicAdd(&s_agg[(size_t)sr * D + lane], val);
    }
}

// ---------------------------------------------------------------------------
// node_out: s_new = s + silu(s_agg)@up_w + up_b ; LayerNorm ; v normalize.
// MFMA, 32 nodes/wave, barrier-free.
// ---------------------------------------------------------------------------
__global__ __launch_bounds__(256, 4) void node_out(
    const float* __restrict__ s, const float* __restrict__ v,
    const float* __restrict__ up_b,
    const float* __restrict__ ln_g, const float* __restrict__ ln_b,
    const float* __restrict__ s_agg, const float* __restrict__ v_agg,
    const unsigned short* __restrict__ WF, float* __restrict__ out) {
  __shared__ __align__(16) char sm[4 * 8704];
  int tid = threadIdx.x, w = tid >> 6, lane = tid & 63;
  int l15 = lane & 15, q = lane >> 4, fb = q * 8;
  char* my = sm + w * 8704;
  int nb = (blockIdx.x * 4 + w) * 32;
  if (nb >= NN) return;

  short8 Bg[2][2];
#pragma unroll
  for (int h = 0; h < 2; ++h)
#pragma unroll
    for (int kt = 0; kt < 2; ++kt) {
      int n = nb + h * 16 + l15; if (n >= NN) n = NN - 1;
      f32x4 g0 = *(const f32x4*)(s_agg + (size_t)n * D + kt * 32 + fb);
      f32x4 g1 = *(const f32x4*)(s_agg + (size_t)n * D + kt * 32 + fb + 4);
#pragma unroll
      for (int c2 = 0; c2 < 4; ++c2) { g0[c2] = silu_f(g0[c2]); g1[c2] = silu_f(g1[c2]); }
      Bg[h][kt] = pack_frag(g0, g1);
    }
  short8 F[4][2]; f32x4 bb[4];
#pragma unroll
  for (int mt = 0; mt < 4; ++mt) {
    F[mt][0] = *(const short8*)(WF + (size_t)(96 + mt * 2 + 0) * 512 + lane * 8);
    F[mt][1] = *(const short8*)(WF + (size_t)(96 + mt * 2 + 1) * 512 + lane * 8);
    bb[mt] = *(const f32x4*)(up_b + mt * 16 + 4 * q);
  }
  f32x4 sn[2][4];
#pragma unroll
  for (int h = 0; h < 2; ++h) {
    int n = nb + h * 16 + l15; if (n >= NN) n = NN - 1;
#pragma unroll
    for (int mt = 0; mt < 4; ++mt) {
      f32x4 acc = {0.f, 0.f, 0.f, 0.f};
      acc = __builtin_amdgcn_mfma_f32_16x16x32_bf16(F[mt][0], Bg[h][0], acc, 0, 0, 0);
      acc = __builtin_amdgcn_mfma_f32_16x16x32_bf16(F[mt][1], Bg[h][1], acc, 0, 0, 0);
      f32x4 sv = *(const f32x4*)(s + (size_t)n * D + mt * 16 + 4 * q);
      sn[h][mt][0] = acc[0] + bb[mt][0] + sv[0];
      sn[h][mt][1] = acc[1] + bb[mt][1] + sv[1];
      sn[h][mt][2] = acc[2] + bb[mt][2] + sv[2];
      sn[h][mt][3] = acc[3] + bb[mt][3] + sv[3];
    }
  }
  // LayerNorm per node (reduce over quads: lanes q=0..3 share l15)
#pragma unroll
  for (int h = 0; h < 2; ++h) {
    float m = 0.f;
#pragma unroll
    for (int mt = 0; mt < 4; ++mt)
      m += sn[h][mt][0] + sn[h][mt][1] + sn[h][mt][2] + sn[h][mt][3];
    m += __shfl_xor(m, 16, 64);
    m += __shfl_xor(m, 32, 64);
    float mu = m * (1.f / 64.f);
    float vv = 0.f;
#pragma unroll
    for (int mt = 0; mt < 4; ++mt)
#pragma unroll
      for (int r = 0; r < 4; ++r) {
        float d = sn[h][mt][r] - mu;
        vv += d * d;
      }
    vv += __shfl_xor(vv, 16, 64);
    vv += __shfl_xor(vv, 32, 64);
    float inv = 1.f / sqrtf(vv * (1.f / 64.f) + 1e-5f);
#pragma unroll
    for (int mt = 0; mt < 4; ++mt) {
      f32x4 lg = *(const f32x4*)(ln_g + mt * 16 + 4 * q);
      f32x4 lb = *(const f32x4*)(ln_b + mt * 16 + 4 * q);
      f32x4 ov;
#pragma unroll
      for (int r = 0; r < 4; ++r) ov[r] = (sn[h][mt][r] - mu) * inv * lg[r] + lb[r];
      *(f32x4*)(my + (((h * 16 + l15) * 68 + mt * 16 + 4 * q) << 2)) = ov;
    }
  }
#pragma unroll
  for (int h = 0; h < 2; ++h)
#pragma unroll
    for (int e = 0; e < 16; ++e) {
      int n = nb + h * 16 + e;
      if (n < NN) {
        float val = *(const float*)(my + (((h * 16 + e) * 68 + lane) << 2));
        out[(size_t)n * D + lane] = val;
      }
    }
  // v path: lanes q<3 handle component q of node (h, l15)
#pragma unroll
  for (int h = 0; h < 2; ++h) {
    int n = nb + h * 16 + l15;
    if (q < 3 && n < NN) {
      float v0 = v[n * 3 + 0] + v_agg[(size_t)n * 3 + 0];
      float v1 = v[n * 3 + 1] + v_agg[(size_t)n * 3 + 1];
      float v2 = v[n * 3 + 2] + v_agg[(size_t)n * 3 + 2];
      float nrm = sqrtf(v0 * v0 + v1 * v1 + v2 * v2);
      float denom = fmaxf(nrm, 1e-6f);
      float val = (q == 0) ? v0 : ((q == 1) ? v1 : v2);
      out[(size_t)NN * D + (size_t)n * 3 + q] = val / denom;
    }
  }
}

// ---------------------------------------------------------------------------
extern "C" void kernel_launch(void* const* d_in, const int* in_sizes, int n_in,
                              void* d_out, int out_size, void* d_ws, size_t ws_size,
                              hipStream_t stream) {
  const float* s         = (const float*)d_in[0];
  const float* v         = (const float*)d_in[1];
  const int*   ei        = (const int*)d_in[2];
  const float* edge_attr = (const float*)d_in[3];
  const float* evu       = (const float*)d_in[4];
  const float* ng_w1     = (const float*)d_in[5];
  const float* ng_b1     = (const float*)d_in[6];
  const float* ng_w2     = (const float*)d_in[7];
  const float* ng_b2     = (const float*)d_in[8];
  const float* eg_w1     = (const float*)d_in[9];
  const float* eg_b1     = (const float*)d_in[10];
  const float* eg_w2     = (const float*)d_in[11];
  const float* eg_b2     = (const float*)d_in[12];
  const float* mg_w1     = (const float*)d_in[13];
  const float* mg_b1     = (const float*)d_in[14];
  const float* mg_w2     = (const float*)d_in[15];
  const float* mg_b2     = (const float*)d_in[16];
  const float* pe_w      = (const float*)d_in[17];
  const float* pe_b      = (const float*)d_in[18];
  const float* up_w      = (const float*)d_in[19];
  const float* up_b      = (const float*)d_in[20];
  const float* ln_g      = (const float*)d_in[21];
  const float* ln_b      = (const float*)d_in[22];
  (void)in_sizes; (void)n_in; (void)out_size; (void)ws_size;

  float* out   = (float*)d_out;
  float* s_agg = (float*)d_ws;                            // NN*64 floats
  float* v_agg = s_agg + (size_t)NN * D;                  // NN*3 floats
  unsigned short* WF = (unsigned short*)(v_agg + (size_t)NN * 3);  // 104 frags * 512 bf16
  float* h_ng  = out;  // d_out[0..NN*64) as scratch; node_out overwrites later

  hipMemsetAsync(d_ws, 0, (size_t)(NN * D + NN * 3) * sizeof(float), stream);

  prep_all<<<26, 256, 0, stream>>>(ng_w2, eg_w1, eg_w2, mg_w1, mg_w2, ng_w1, up_w, WF);

  int node_blocks = (NN + 127) / 128;  // 32 nodes/wave * 4 waves
  node_pre<<<node_blocks, 256, 0, stream>>>(s, ng_b1, WF, h_ng);

  edge_mfma<<<NE / 128, 256, 0, stream>>>(
      v, ei, edge_attr, evu,
      ng_w1, ng_b2, eg_w1, eg_b1, eg_b2,
      mg_b1, mg_b2, pe_w, pe_b, h_ng, WF, s_agg, v_agg);

  node_out<<<node_blocks, 256, 0, stream>>>(
      s, v, up_b, ln_g, ln_b, s_agg, v_agg, WF, out);
}